// Round 5
// baseline (150.871 us; speedup 1.0000x reference)
//
#include <hip/hip_runtime.h>

// EmbeddingDistance: out[b] = 1 - dot(mean_i norm(x1[b,i,:]), mean_j norm(x2[b,j,:]))
// x1, x2: (16, 4096, 256) fp32.
// R4: global_load_lds ingest, 1 wave/block (uniform LDS base, no barriers),
// shallow ring (8 DMA in flight), asm-waitcnt with memory clobber.

constexpr int D = 256;             // embedding dim (1 KB per row)
constexpr int S = 4096;            // rows per sequence
constexpr int B = 16;              // batches
constexpr int NSEQ = 2 * B;        // 32 sequences
constexpr int NROWS = NSEQ * S;    // 131072 rows

constexpr int NBLK = 2048;                              // 1 wave/block, 8/CU
constexpr int BLOCKS_PER_SEQ = NBLK / NSEQ;             // 64
constexpr int ROWS_PER_BLOCK = NROWS / NBLK;            // 64
constexpr int ROWS_PER_SLOT = 4;
constexpr int SLOT_BYTES = ROWS_PER_SLOT * D * 4;       // 4 KB
constexpr int NSLOTS = 4;                               // 16 KB ring
constexpr int NITER = ROWS_PER_BLOCK / ROWS_PER_SLOT;   // 16
constexpr float EPS2 = 1e-16f;

// One global_load_lds: 64 lanes x 16 B = 1 KB = one row.
// LDS dest = uniform base + lane*16; global src = per-lane pointer.
__device__ __forceinline__ void dma_row(const float* g, char* lds) {
    __builtin_amdgcn_global_load_lds(
        (const __attribute__((address_space(1))) void*)g,
        (__attribute__((address_space(3))) void*)lds, 16, 0, 0);
}

template <int CTRL>
__device__ __forceinline__ float dpp_add(float x) {
    int xi = __builtin_bit_cast(int, x);
    int yi = __builtin_amdgcn_update_dpp(0, xi, CTRL, 0xf, 0xf, true);
    return x + __builtin_bit_cast(float, yi);
}

// Sum across each 32-lane half (4 DPP adds + 1 ds_swizzle xor16).
__device__ __forceinline__ float half_reduce(float x) {
    x = dpp_add<0xB1>(x);    // xor 1
    x = dpp_add<0x4E>(x);    // xor 2
    x = dpp_add<0x141>(x);   // row_half_mirror
    x = dpp_add<0x140>(x);   // row_mirror
    int xi = __builtin_bit_cast(int, x);
    int yi = __builtin_amdgcn_ds_swizzle(xi, 0x401F);  // xor 16
    return x + __builtin_bit_cast(float, yi);
}

// ---- Kernel 1: one wave streams 64 contiguous rows through a 4-slot LDS
// ring filled by global_load_lds.  Rows consumed 2 at a time (lanes 0-31 ->
// even row, 32-63 -> odd row; lane owns 8 floats of its row).
template <bool USE_PARTIALS>
__global__ __launch_bounds__(64) void row_norm_sum_kernel(
    const float* __restrict__ x1, const float* __restrict__ x2,
    float* __restrict__ sums /* USE_PARTIALS ? [NBLK][D] : [NSEQ][D] */)
{
    __shared__ char ring[NSLOTS * SLOT_BYTES];           // 16 KB, block=wave

    const int lane = threadIdx.x;                        // 0..63
    const int half = lane >> 5;
    const int l    = lane & 31;

    const int seq = blockIdx.x / BLOCKS_PER_SEQ;         // 0..31
    const int r0  = (blockIdx.x % BLOCKS_PER_SEQ) * ROWS_PER_BLOCK;
    const float* __restrict__ src =
        ((seq & 1) ? x2 : x1) + (size_t)(seq >> 1) * S * D + (size_t)r0 * D;
    const float* gl = src + 4 * lane;                    // lane's 16 B of a row

    // Prologue: fill slots 0,1 (8 DMA instructions in flight).
    #pragma unroll
    for (int s = 0; s < 2; ++s)
        #pragma unroll
        for (int r = 0; r < ROWS_PER_SLOT; ++r)
            dma_row(gl + (size_t)(s * ROWS_PER_SLOT + r) * D,
                    ring + s * SLOT_BYTES + r * 1024);

    float4 acc_lo = make_float4(0.f, 0.f, 0.f, 0.f);
    float4 acc_hi = make_float4(0.f, 0.f, 0.f, 0.f);

    #pragma unroll
    for (int i = 0; i < NITER; ++i) {
        // Retire slot i (4 DMAs); slot i+1 stays in flight.
        if (i < NITER - 1) asm volatile("s_waitcnt vmcnt(4)" ::: "memory");
        else               asm volatile("s_waitcnt vmcnt(0)" ::: "memory");

        if (i + 2 < NITER) {     // refill: issue slot i+2
            char* sl = ring + ((i + 2) & (NSLOTS - 1)) * SLOT_BYTES;
            #pragma unroll
            for (int r = 0; r < ROWS_PER_SLOT; ++r)
                dma_row(gl + (size_t)((i + 2) * ROWS_PER_SLOT + r) * D,
                        sl + r * 1024);
        }

        const char* sl = ring + (i & (NSLOTS - 1)) * SLOT_BYTES;
        #pragma unroll
        for (int p = 0; p < 2; ++p) {          // 2 row-pairs per slot
            const float* rowp = (const float*)(sl + p * 2048 + half * 1024);
            const float4 vlo = *(const float4*)(rowp + 4 * l);
            const float4 vhi = *(const float4*)(rowp + 128 + 4 * l);
            float ss = vlo.x * vlo.x + vlo.y * vlo.y
                     + vlo.z * vlo.z + vlo.w * vlo.w
                     + vhi.x * vhi.x + vhi.y * vhi.y
                     + vhi.z * vhi.z + vhi.w * vhi.w;
            ss = half_reduce(ss);              // per-row ||x||^2
            const float sc = rsqrtf(fmaxf(ss, EPS2));
            acc_lo.x += vlo.x * sc;  acc_lo.y += vlo.y * sc;
            acc_lo.z += vlo.z * sc;  acc_lo.w += vlo.w * sc;
            acc_hi.x += vhi.x * sc;  acc_hi.y += vhi.y * sc;
            acc_hi.z += vhi.z * sc;  acc_hi.w += vhi.w * sc;
        }
    }

    // Cross-half combine: lane l and lane l+32 hold the same dims.
    float4 tot_lo, tot_hi;
    tot_lo.x = acc_lo.x + __shfl_xor(acc_lo.x, 32, 64);
    tot_lo.y = acc_lo.y + __shfl_xor(acc_lo.y, 32, 64);
    tot_lo.z = acc_lo.z + __shfl_xor(acc_lo.z, 32, 64);
    tot_lo.w = acc_lo.w + __shfl_xor(acc_lo.w, 32, 64);
    tot_hi.x = acc_hi.x + __shfl_xor(acc_hi.x, 32, 64);
    tot_hi.y = acc_hi.y + __shfl_xor(acc_hi.y, 32, 64);
    tot_hi.z = acc_hi.z + __shfl_xor(acc_hi.z, 32, 64);
    tot_hi.w = acc_hi.w + __shfl_xor(acc_hi.w, 32, 64);

    if (half == 0) {
        if (USE_PARTIALS) {
            float* dst = sums + (size_t)blockIdx.x * D;
            *(float4*)(dst + 4 * l)       = tot_lo;
            *(float4*)(dst + 128 + 4 * l) = tot_hi;
        } else {
            float* dst = sums + (size_t)seq * D;
            atomicAdd(dst + 4 * l + 0, tot_lo.x);
            atomicAdd(dst + 4 * l + 1, tot_lo.y);
            atomicAdd(dst + 4 * l + 2, tot_lo.z);
            atomicAdd(dst + 4 * l + 3, tot_lo.w);
            atomicAdd(dst + 128 + 4 * l + 0, tot_hi.x);
            atomicAdd(dst + 128 + 4 * l + 1, tot_hi.y);
            atomicAdd(dst + 128 + 4 * l + 2, tot_hi.z);
            atomicAdd(dst + 128 + 4 * l + 3, tot_hi.w);
        }
    }
}

// ---- Kernel 2 (partials path): per batch, reduce the 64 block-partials of
// each input, dot, block-reduce, write 1 - dot/S^2.
__global__ __launch_bounds__(256) void finalize_partials_kernel(
    const float* __restrict__ partials, float* __restrict__ out)
{
    const int b = blockIdx.x;
    const int t = threadIdx.x;
    const int w = t >> 6, lane = t & 63;

    const float* p1 = partials + ((size_t)(2 * b + 0) * BLOCKS_PER_SEQ) * D + t;
    const float* p2 = partials + ((size_t)(2 * b + 1) * BLOCKS_PER_SEQ) * D + t;
    float s1 = 0.f, s2 = 0.f;
    #pragma unroll 8
    for (int k = 0; k < BLOCKS_PER_SEQ; ++k) {
        s1 += p1[(size_t)k * D];
        s2 += p2[(size_t)k * D];
    }
    float d = s1 * s2;
    #pragma unroll
    for (int m = 1; m < 64; m <<= 1) d += __shfl_xor(d, m, 64);

    __shared__ float r[4];
    if (lane == 0) r[w] = d;
    __syncthreads();
    if (t == 0) {
        const float inv = 1.0f / ((float)S * (float)S);
        out[b] = 1.0f - (r[0] + r[1] + r[2] + r[3]) * inv;
    }
}

// ---- Kernel 2 (atomic fallback): sums already fully reduced per sequence.
__global__ __launch_bounds__(64) void finalize_kernel(
    const float* __restrict__ sums, float* __restrict__ out)
{
    const int b = blockIdx.x;
    const int lane = threadIdx.x;
    const float4 a = *(const float4*)(sums + (size_t)(2 * b + 0) * D + lane * 4);
    const float4 c = *(const float4*)(sums + (size_t)(2 * b + 1) * D + lane * 4);
    float d = a.x * c.x + a.y * c.y + a.z * c.z + a.w * c.w;
    #pragma unroll
    for (int m = 1; m < 64; m <<= 1) d += __shfl_xor(d, m, 64);
    if (lane == 0) {
        const float inv = 1.0f / ((float)S * (float)S);
        out[b] = 1.0f - d * inv;
    }
}

extern "C" void kernel_launch(void* const* d_in, const int* in_sizes, int n_in,
                              void* d_out, int out_size, void* d_ws, size_t ws_size,
                              hipStream_t stream) {
    const float* x1 = (const float*)d_in[0];
    const float* x2 = (const float*)d_in[1];
    float* out = (float*)d_out;
    float* ws = (float*)d_ws;

    const size_t partial_bytes = (size_t)NBLK * D * sizeof(float);   // 2 MB
    if (ws_size >= partial_bytes) {
        row_norm_sum_kernel<true><<<NBLK, 64, 0, stream>>>(x1, x2, ws);
        finalize_partials_kernel<<<B, 256, 0, stream>>>(ws, out);
    } else {
        hipMemsetAsync(ws, 0, (size_t)NSEQ * D * sizeof(float), stream);
        row_norm_sum_kernel<false><<<NBLK, 64, 0, stream>>>(x1, x2, ws);
        finalize_kernel<<<B, 64, 0, stream>>>(ws, out);
    }
}

// Round 6
// 147.227 us; speedup vs baseline: 1.0248x; 1.0248x over previous
//
#include <hip/hip_runtime.h>

// EmbeddingDistance: out[b] = 1 - dot(mean_i norm(x1[b,i,:]), mean_j norm(x2[b,j,:]))
// x1, x2: (16, 4096, 256) fp32.  134 MB single-pass read.
// Best variant (R1): 2048 blocks x 256 thr, 4-row ILP, wave-per-row shfl
// reduction, block partials + separate finalize.  Measured 41.5-41.9 us
// kernel-1 = 3.2 TB/s ingest = device read-path ceiling (m13 copy reads at
// 3.15 TB/s; R2's DPP and R4's global_load_lds DMA both converge here too).

constexpr int D = 256;            // embedding dim
constexpr int S = 4096;           // segments (rows) per batch
constexpr int B = 16;             // batches
constexpr int BLOCKS_PER_PAIR = 64;
constexpr int WAVES_PER_BLOCK = 4;              // 256 threads
constexpr int WAVES_PER_PAIR  = BLOCKS_PER_PAIR * WAVES_PER_BLOCK;  // 256
constexpr int ROWS_PER_WAVE   = S / WAVES_PER_PAIR;                 // 16
constexpr int NPAIR = 2 * B;                                        // 32
constexpr int NBLK1 = NPAIR * BLOCKS_PER_PAIR;                      // 2048
constexpr float EPS2 = 1e-16f;    // eps^2 for the norm clamp

// ---- Kernel 1: one wave per row, lane l owns dims [4l, 4l+4).
// Unroll 4 rows -> 4 independent load+shfl chains.  Block-level LDS
// reduction, then either a partial-store (preferred) or atomicAdd.
template <bool USE_PARTIALS>
__global__ __launch_bounds__(256) void row_norm_sum_kernel(
    const float* __restrict__ x1, const float* __restrict__ x2,
    float* __restrict__ sums /* USE_PARTIALS ? [NBLK1][D] : [NPAIR][D] */)
{
    const int pair = blockIdx.x / BLOCKS_PER_PAIR;      // 0..31
    const int blk  = blockIdx.x % BLOCKS_PER_PAIR;      // 0..63
    const int w    = threadIdx.x >> 6;                  // 0..3
    const int lane = threadIdx.x & 63;
    const int wv   = blk * WAVES_PER_BLOCK + w;         // 0..255 within pair

    const int batch = pair >> 1;
    const float* __restrict__ src = (pair & 1) ? x2 : x1;
    src += (size_t)batch * S * D;

    float4 acc = make_float4(0.f, 0.f, 0.f, 0.f);

    #pragma unroll
    for (int i = 0; i < ROWS_PER_WAVE; i += 4) {
        float4 v[4];
        float  ss[4];
        #pragma unroll
        for (int k = 0; k < 4; ++k) {
            const int r = wv + (i + k) * WAVES_PER_PAIR;
            v[k] = *(const float4*)(src + (size_t)r * D + lane * 4);
        }
        #pragma unroll
        for (int k = 0; k < 4; ++k)
            ss[k] = v[k].x * v[k].x + v[k].y * v[k].y
                  + v[k].z * v[k].z + v[k].w * v[k].w;
        // 4 independent butterfly chains (6 steps each) — latency overlaps.
        #pragma unroll
        for (int m = 1; m < 64; m <<= 1) {
            #pragma unroll
            for (int k = 0; k < 4; ++k)
                ss[k] += __shfl_xor(ss[k], m, 64);
        }
        #pragma unroll
        for (int k = 0; k < 4; ++k) {
            const float s = rsqrtf(fmaxf(ss[k], EPS2));
            acc.x += v[k].x * s;
            acc.y += v[k].y * s;
            acc.z += v[k].z * s;
            acc.w += v[k].w * s;
        }
    }

    // Block reduction across the 4 waves.
    __shared__ float lds[WAVES_PER_BLOCK][D];
    *(float4*)&lds[w][lane * 4] = acc;
    __syncthreads();

    const int t = threadIdx.x;
    const float val = lds[0][t] + lds[1][t] + lds[2][t] + lds[3][t];
    if (USE_PARTIALS) {
        sums[(size_t)blockIdx.x * D + t] = val;     // no atomics, no memset
    } else {
        atomicAdd(&sums[(size_t)pair * D + t], val);
    }
}

// ---- Kernel 2 (partials path): per batch, reduce 64-block partials for both
// inputs, dot them, block-reduce, write 1 - dot/S^2.
__global__ __launch_bounds__(256) void finalize_partials_kernel(
    const float* __restrict__ partials, float* __restrict__ out)
{
    const int b = blockIdx.x;
    const int t = threadIdx.x;
    const int w = t >> 6, lane = t & 63;

    const float* p1 = partials + ((size_t)(2 * b + 0) * BLOCKS_PER_PAIR) * D + t;
    const float* p2 = partials + ((size_t)(2 * b + 1) * BLOCKS_PER_PAIR) * D + t;
    float s1 = 0.f, s2 = 0.f;
    #pragma unroll 8
    for (int k = 0; k < BLOCKS_PER_PAIR; ++k) {
        s1 += p1[(size_t)k * D];
        s2 += p2[(size_t)k * D];
    }
    float d = s1 * s2;
    #pragma unroll
    for (int m = 1; m < 64; m <<= 1) d += __shfl_xor(d, m, 64);

    __shared__ float r[WAVES_PER_BLOCK];
    if (lane == 0) r[w] = d;
    __syncthreads();
    if (t == 0) {
        const float inv = 1.0f / ((float)S * (float)S);
        out[b] = 1.0f - (r[0] + r[1] + r[2] + r[3]) * inv;
    }
}

// ---- Kernel 2 (atomic fallback path): sums are already fully reduced.
__global__ __launch_bounds__(64) void finalize_kernel(
    const float* __restrict__ sums, float* __restrict__ out)
{
    const int b = blockIdx.x;
    const int lane = threadIdx.x;
    const float4 a = *(const float4*)(sums + (size_t)(2 * b + 0) * D + lane * 4);
    const float4 c = *(const float4*)(sums + (size_t)(2 * b + 1) * D + lane * 4);
    float d = a.x * c.x + a.y * c.y + a.z * c.z + a.w * c.w;
    #pragma unroll
    for (int m = 1; m < 64; m <<= 1) d += __shfl_xor(d, m, 64);
    if (lane == 0) {
        const float inv = 1.0f / ((float)S * (float)S);
        out[b] = 1.0f - d * inv;
    }
}

extern "C" void kernel_launch(void* const* d_in, const int* in_sizes, int n_in,
                              void* d_out, int out_size, void* d_ws, size_t ws_size,
                              hipStream_t stream) {
    const float* x1 = (const float*)d_in[0];
    const float* x2 = (const float*)d_in[1];
    float* out = (float*)d_out;
    float* ws = (float*)d_ws;

    const size_t partial_bytes = (size_t)NBLK1 * D * sizeof(float);   // 2 MB
    if (ws_size >= partial_bytes) {
        row_norm_sum_kernel<true><<<NBLK1, 256, 0, stream>>>(x1, x2, ws);
        finalize_partials_kernel<<<B, 256, 0, stream>>>(ws, out);
    } else {
        hipMemsetAsync(ws, 0, (size_t)NPAIR * D * sizeof(float), stream);
        row_norm_sum_kernel<false><<<NBLK1, 256, 0, stream>>>(x1, x2, ws);
        finalize_kernel<<<B, 64, 0, stream>>>(ws, out);
    }
}